// Round 7
// baseline (337.058 us; speedup 1.0000x reference)
//
#include <hip/hip_runtime.h>
#include <stdint.h>

// ---------- sizes (fixed by setup_inputs) ----------
#define BATCH   65536
#define FIN     32        // layer-1 in
#define HID     64        // layer-1 out / layer-2 in
#define NOUT    2048      // layer-2 out
#define NC      8         // bases per element
#define NF      9         // features per element (silu + 8 bases)
#define K1      288       // FIN*NF
#define K2      576       // HID*NF

// ---------- GEMM2 tiling (m201-style 8-wave 256x256, BK=64) ----------
#define BM      256
#define BN      256
#define BK2     64
#define KT2     9         // K2 / BK2

typedef __bf16 bf16x8 __attribute__((ext_vector_type(8)));
typedef float f32x4 __attribute__((ext_vector_type(4)));

// ---------- helpers ----------
__device__ __forceinline__ uint16_t f2bf(float f) {
    uint32_t u = __builtin_bit_cast(uint32_t, f);
    uint32_t r = (u + 0x7fffu + ((u >> 16) & 1u)) >> 16;
    return (uint16_t)r;
}
__device__ __forceinline__ float silu_f(float v) {
    return v / (1.f + __expf(-v));
}

// Closed-form uniform cubic B-spline bases. Knots g[t]=(t-3)*0.4-1, t=0..11.
__device__ __forceinline__ void bspline8u(float xv, float out[8]) {
    float s = (xv + 2.2f) * 2.5f;
    int c = (int)floorf(s);
    float gc = (float)(c - 3) * 0.4f - 1.0f;
    float u = (xv - gc) * 2.5f;
    float u1 = 1.f - u;
    float uu = u * u, u3 = uu * u;
    float w0 = u1 * u1 * u1 * (1.f / 6.f);
    float w1 = (3.f * u3 - 6.f * uu + 4.f) * (1.f / 6.f);
    float w2 = (-3.f * u3 + 3.f * uu + 3.f * u + 1.f) * (1.f / 6.f);
    float w3 = u3 * (1.f / 6.f);
#pragma unroll
    for (int t = 0; t < 8; t++) {
        int d = c - t;
        out[t] = (d == 0) ? w3 : (d == 1) ? w2 : (d == 2) ? w1 : (d == 3) ? w0 : 0.f;
    }
}

// ---------- pack kernels ----------
__global__ void pack_w1(const float* __restrict__ bw1, const float* __restrict__ sw1,
                        const float* __restrict__ ss1, uint16_t* __restrict__ w1L) {
    int idx = blockIdx.x * 256 + threadIdx.x;
    if (idx >= 64 * K1) return;
    int o = idx / K1, k = idx % K1;
    int i = k / 9, j = k % 9;
    float v = (j == 0) ? bw1[o * FIN + i]
                       : sw1[(o * FIN + i) * NC + (j - 1)] * ss1[o * FIN + i];
    w1L[idx] = f2bf(v);
}

__global__ void pack_w2(const float* __restrict__ bw2, const float* __restrict__ sw2,
                        const float* __restrict__ ss2, uint16_t* __restrict__ w2p) {
    int idx = blockIdx.x * 256 + threadIdx.x;
    if (idx >= NOUT * K2) return;
    int n = idx / K2, k = idx % K2;
    int j = k >> 6, i = k & 63;
    float v = (j == 0) ? bw2[n * HID + i]
                       : sw2[(n * HID + i) * NC + (j - 1)] * ss2[n * HID + i];
    w2p[idx] = f2bf(v);
}

// ---------- fused LN + featurize1 + MFMA layer1 + featurize2 (r6, verified) ----------
#define FBR    64
#define A1LD   296
#define S2LD   584
__global__ __launch_bounds__(256) void featurize(
    const float* __restrict__ x, const float* __restrict__ lnw, const float* __restrict__ lnb,
    const uint16_t* __restrict__ w1L, uint16_t* __restrict__ a2) {

    __shared__ __align__(16) char fsm[75776];
    uint16_t* w1s = (uint16_t*)fsm;              // [64][296]
    uint16_t* a1s = (uint16_t*)(fsm + 37888);    // [64][296]
    uint16_t* s2  = (uint16_t*)fsm;              // [64][584] (phase 3)

    const int tid = threadIdx.x;
    const int wv = tid >> 6, lane = tid & 63;
    const int rowBase = blockIdx.x * FBR;

#pragma unroll
    for (int t = 0; t < 9; ++t) {
        int idx = t * 256 + tid;
        int o = idx / 36, cc = idx % 36;
        uint4 v = *(const uint4*)(w1L + idx * 8);
        *(uint4*)&w1s[o * A1LD + cc * 8] = v;
    }

    const int prow = tid >> 2, pq = tid & 3;
    const float* xp = x + (size_t)(rowBase + prow) * FIN + pq * 8;
    float xv[8];
    *(float4*)&xv[0] = ((const float4*)xp)[0];
    *(float4*)&xv[4] = ((const float4*)xp)[1];
    float s = 0.f, s2v = 0.f;
#pragma unroll
    for (int j = 0; j < 8; j++) { s += xv[j]; s2v += xv[j] * xv[j]; }
    s += __shfl_xor(s, 1);  s2v += __shfl_xor(s2v, 1);
    s += __shfl_xor(s, 2);  s2v += __shfl_xor(s2v, 2);
    const float mu = s * (1.f / 32.f);
    const float var = s2v * (1.f / 32.f) - mu * mu;
    const float rstd = rsqrtf(var + 1e-5f);

    float wl[8], bl[8];
    *(float4*)&wl[0] = ((const float4*)(lnw + pq * 8))[0];
    *(float4*)&wl[4] = ((const float4*)(lnw + pq * 8))[1];
    *(float4*)&bl[0] = ((const float4*)(lnb + pq * 8))[0];
    *(float4*)&bl[4] = ((const float4*)(lnb + pq * 8))[1];

    __align__(16) uint16_t tmp[72];
#pragma unroll
    for (int ii = 0; ii < 8; ii++) {
        float xn = (xv[ii] - mu) * rstd * wl[ii] + bl[ii];
        tmp[ii * 9] = f2bf(silu_f(xn));
        float bs[8];
        bspline8u(xn, bs);
#pragma unroll
        for (int j = 0; j < 8; j++) tmp[ii * 9 + 1 + j] = f2bf(bs[j]);
    }
    {
        uint16_t* dst = &a1s[prow * A1LD + pq * 72];
#pragma unroll
        for (int q = 0; q < 9; q++) *(uint4*)(dst + q * 8) = *(const uint4*)&tmp[q * 8];
    }
    __syncthreads();

    f32x4 acc[4];
#pragma unroll
    for (int n = 0; n < 4; n++) acc[n] = (f32x4){0.f, 0.f, 0.f, 0.f};
    const int arow = wv * 16 + (lane & 15);
    const int koff = (lane >> 4) * 8;
#pragma unroll
    for (int ks = 0; ks < 9; ++ks) {
        bf16x8 af = *(const bf16x8*)&a1s[arow * A1LD + ks * 32 + koff];
#pragma unroll
        for (int n = 0; n < 4; n++) {
            bf16x8 bv = *(const bf16x8*)&w1s[(n * 16 + (lane & 15)) * A1LD + ks * 32 + koff];
            acc[n] = __builtin_amdgcn_mfma_f32_16x16x32_bf16(af, bv, acc[n], 0, 0, 0);
        }
    }
    __syncthreads();

    const int r0 = wv * 16 + ((lane >> 4) << 2);
    const int cb = lane & 15;
#pragma unroll
    for (int n = 0; n < 4; n++)
#pragma unroll
        for (int r = 0; r < 4; r++) {
            float h = acc[n][r];
            float o9[9];
            o9[0] = silu_f(h);
            bspline8u(h, &o9[1]);
            uint16_t* op = &s2[(size_t)(r0 + r) * S2LD + n * 16 + cb];
#pragma unroll
            for (int j = 0; j < 9; j++) op[j * 64] = f2bf(o9[j]);
        }
    __syncthreads();

#pragma unroll
    for (int q = 0; q < 18; ++q) {
        int g = q * 256 + tid;
        int row = g / 72, c = g % 72;
        uint4 v = *(const uint4*)&s2[row * S2LD + c * 8];
        *(uint4*)(a2 + (size_t)(rowBase + row) * K2 + c * 8) = v;
    }
}

// ---------- GEMM2: (65536 x 576) x (576 x 2048), m201-style schedule ----------
// A [M][576] bf16 row-major; Bt [N][576] bf16 row-major; C [M][N] fp32.
// 8 waves (2M x 4N), wave tile 128x64. K-tile = 64 (9 tiles). LDS: per matrix
// a 4-slot ring of half-tiles (128 rows x 64 k = 16 KiB); slot(tile,half) =
// (2t+h)&3. 4 phases/tile, 16 MFMA each. Staging stream (2 gloads/phase):
// P1:B1(t+1) P2:A1(t+1) P3:B0(t+2) P4:A0(t+2); single vmcnt(4)/tile (t=7: 0).
// Swizzle (rule 21, both sides): LDS[row][slot16B] = G[row][slot^(row&7)];
// reads XOR the wanted slot with row&7.
__device__ __forceinline__ void gload16(const uint16_t* g, const uint16_t* l) {
    __builtin_amdgcn_global_load_lds(
        (const __attribute__((address_space(1))) void*)g,
        (__attribute__((address_space(3))) void*)l, 16, 0, 0);
}

__global__ __launch_bounds__(512, 2) void gemm2_kernel(const uint16_t* __restrict__ A,
                                                       const uint16_t* __restrict__ Bt,
                                                       float* __restrict__ C) {
    __shared__ __align__(16) uint16_t lA[4][8192];   // 64 KiB
    __shared__ __align__(16) uint16_t lB[4][8192];   // 64 KiB

    const int tid = threadIdx.x;
    const int wv = tid >> 6, lane = tid & 63;
    const int wr = wv >> 2, wc = wv & 3;            // 2 x 4 wave grid

    // XCD-aware bijective swizzle (2048 blocks, 2048 % 8 == 0)
    const uint32_t bid = blockIdx.x;
    const uint32_t wk = (bid & 7u) * 256u + (bid >> 3);
    const uint32_t ntile = wk & 7u, mtile = wk >> 3;

    // Staging source (per-thread, pre-swizzled column):
    // thread writes LDS row (i*64 + tid>>3), 16B slot (tid&7);
    // source col-slot = (tid&7) ^ ((tid>>3)&7).
    const int xcol = (((tid & 7) ^ ((tid >> 3) & 7)) << 3);
    const uint16_t* gAb = A  + (size_t)(mtile * BM + (tid >> 3)) * K2 + xcol;
    const uint16_t* gBb = Bt + (size_t)(ntile * BN + (tid >> 3)) * K2 + xcol;

#define ST_A(tt, h) do { \
    gload16(gAb + (size_t)((h) * 128) * K2 + (tt) * BK2,      &lA[(2*(tt)+(h)) & 3][tid * 8]); \
    gload16(gAb + (size_t)((h) * 128 + 64) * K2 + (tt) * BK2, &lA[(2*(tt)+(h)) & 3][4096 + tid * 8]); } while (0)
#define ST_B(tt, h) do { \
    gload16(gBb + (size_t)((h) * 128) * K2 + (tt) * BK2,      &lB[(2*(tt)+(h)) & 3][tid * 8]); \
    gload16(gBb + (size_t)((h) * 128 + 64) * K2 + (tt) * BK2, &lB[(2*(tt)+(h)) & 3][4096 + tid * 8]); } while (0)

    // Fragment read addressing (within a half-tile slot):
    // row = frag*16 + (lane&15); byte = row*128 + ((ks*4 + lane>>4)^(row&7))*16.
    // row&7 == lane&7. 16-lane groups hit 8 distinct 16B slots twice -> 2-way.
    const int arow = (lane & 15) * 64;
    const int swz0 = (((lane >> 4)     ) ^ (lane & 7)) << 3;   // ks=0, elems
    const int swz1 = (((lane >> 4) | 4 ) ^ (lane & 7)) << 3;   // ks=1
    const int bbase = (wc & 1) * 4096;                          // n-rows 64..127 half

#define LDA(sl, mf, ks) (*(const bf16x8*)&lA[sl][(mf) * 1024 + arow + ((ks) ? swz1 : swz0)])
#define LDB(sl, nf, ks) (*(const bf16x8*)&lB[sl][bbase + (nf) * 1024 + arow + ((ks) ? swz1 : swz0)])

    f32x4 acc[8][4];
#pragma unroll
    for (int m = 0; m < 8; m++)
#pragma unroll
        for (int n = 0; n < 4; n++) acc[m][n] = (f32x4){0.f, 0.f, 0.f, 0.f};

    // Prologue: A0(0),B0(0),B1(0),A1(0),B0(1),A0(1) = 12 gloads.
    // vmcnt(4) -> tile 0 fully resident; B0(1),A0(1) may remain in flight.
    ST_A(0, 0); ST_B(0, 0); ST_B(0, 1); ST_A(0, 1); ST_B(1, 0); ST_A(1, 0);
    asm volatile("s_waitcnt vmcnt(4)" ::: "memory");
    asm volatile("s_barrier" ::: "memory");

#pragma unroll
    for (int t = 0; t < KT2; ++t) {
        const int sa = (2 * t + wr) & 3;          // this wave's A half-slot
        const int sb = (2 * t + (wc >> 1)) & 3;   // this wave's B half-slot
        bf16x8 a0[4][2], a1[4][2], b0[2][2], b1[2][2];

        // ---- P1 (q00): read A m0..3 + B n0..1; stage B1(t+1) ----
#pragma unroll
        for (int mf = 0; mf < 4; ++mf) { a0[mf][0] = LDA(sa, mf, 0); a0[mf][1] = LDA(sa, mf, 1); }
#pragma unroll
        for (int nf = 0; nf < 2; ++nf) { b0[nf][0] = LDB(sb, nf, 0); b0[nf][1] = LDB(sb, nf, 1); }
        if (t + 1 < KT2) ST_B(t + 1, 1);
        asm volatile("s_barrier" ::: "memory");
        asm volatile("s_waitcnt lgkmcnt(0)" ::: "memory");
        __builtin_amdgcn_sched_barrier(0);
        __builtin_amdgcn_s_setprio(1);
#pragma unroll
        for (int mf = 0; mf < 4; ++mf)
#pragma unroll
            for (int nf = 0; nf < 2; ++nf)
#pragma unroll
                for (int ks = 0; ks < 2; ++ks)
                    acc[mf][nf] = __builtin_amdgcn_mfma_f32_16x16x32_bf16(a0[mf][ks], b0[nf][ks], acc[mf][nf], 0, 0, 0);
        __builtin_amdgcn_s_setprio(0);
        asm volatile("s_barrier" ::: "memory");

        // ---- P2 (q01): read B n2..3; stage A1(t+1) ----
#pragma unroll
        for (int nf = 0; nf < 2; ++nf) { b1[nf][0] = LDB(sb, nf + 2, 0); b1[nf][1] = LDB(sb, nf + 2, 1); }
        if (t + 1 < KT2) ST_A(t + 1, 1);
        asm volatile("s_barrier" ::: "memory");
        asm volatile("s_waitcnt lgkmcnt(0)" ::: "memory");
        __builtin_amdgcn_sched_barrier(0);
        __builtin_amdgcn_s_setprio(1);
#pragma unroll
        for (int mf = 0; mf < 4; ++mf)
#pragma unroll
            for (int nf = 0; nf < 2; ++nf)
#pragma unroll
                for (int ks = 0; ks < 2; ++ks)
                    acc[mf][nf + 2] = __builtin_amdgcn_mfma_f32_16x16x32_bf16(a0[mf][ks], b1[nf][ks], acc[mf][nf + 2], 0, 0, 0);
        __builtin_amdgcn_s_setprio(0);
        asm volatile("s_barrier" ::: "memory");

        // ---- P3 (q10): read A m4..7; stage B0(t+2) ----
#pragma unroll
        for (int mf = 0; mf < 4; ++mf) { a1[mf][0] = LDA(sa, mf + 4, 0); a1[mf][1] = LDA(sa, mf + 4, 1); }
        if (t + 2 < KT2) ST_B(t + 2, 0);
        asm volatile("s_barrier" ::: "memory");
        asm volatile("s_waitcnt lgkmcnt(0)" ::: "memory");
        __builtin_amdgcn_sched_barrier(0);
        __builtin_amdgcn_s_setprio(1);
#pragma unroll
        for (int mf = 0; mf < 4; ++mf)
#pragma unroll
            for (int nf = 0; nf < 2; ++nf)
#pragma unroll
                for (int ks = 0; ks < 2; ++ks)
                    acc[mf + 4][nf] = __builtin_amdgcn_mfma_f32_16x16x32_bf16(a1[mf][ks], b0[nf][ks], acc[mf + 4][nf], 0, 0, 0);
        __builtin_amdgcn_s_setprio(0);
        asm volatile("s_barrier" ::: "memory");

        // ---- P4 (q11): no ds_reads; stage A0(t+2); vmcnt checkpoint ----
        if (t + 2 < KT2) ST_A(t + 2, 0);
        __builtin_amdgcn_s_setprio(1);
#pragma unroll
        for (int mf = 0; mf < 4; ++mf)
#pragma unroll
            for (int nf = 0; nf < 2; ++nf)
#pragma unroll
                for (int ks = 0; ks < 2; ++ks)
                    acc[mf + 4][nf + 2] = __builtin_amdgcn_mfma_f32_16x16x32_bf16(a1[mf][ks], b1[nf][ks], acc[mf + 4][nf + 2], 0, 0, 0);
        __builtin_amdgcn_s_setprio(0);
        // Ledger: steady outstanding after P4 = B0(t+2),A0(t+2) = 4 loads ->
        // vmcnt(4) proves B1(t+1),A1(t+1) (and older) resident. t==7: need all
        // of tile 8 (A1(8) staged this tile P2) -> vmcnt(0) (final drain).
        if (t <= KT2 - 3)      asm volatile("s_waitcnt vmcnt(4)" ::: "memory");
        else if (t == KT2 - 2) asm volatile("s_waitcnt vmcnt(0)" ::: "memory");
        if (t < KT2 - 1) asm volatile("s_barrier" ::: "memory");
    }
#undef ST_A
#undef ST_B
#undef LDA
#undef LDB

    // ---- epilogue: C layout col=lane&15, row=(lane>>4)*4+r ----
    const int crow0 = (int)mtile * BM + wr * 128 + ((lane >> 4) << 2);
    const int ccol0 = (int)ntile * BN + wc * 64 + (lane & 15);
#pragma unroll
    for (int m = 0; m < 8; ++m)
#pragma unroll
        for (int n = 0; n < 4; ++n) {
            float* cp = C + (size_t)(crow0 + m * 16) * NOUT + ccol0 + n * 16;
#pragma unroll
            for (int r = 0; r < 4; ++r) cp[(size_t)r * NOUT] = acc[m][n][r];
        }
}

// ---------- launcher ----------
extern "C" void kernel_launch(void* const* d_in, const int* in_sizes, int n_in,
                              void* d_out, int out_size, void* d_ws, size_t ws_size,
                              hipStream_t stream) {
    const float* x    = (const float*)d_in[0];
    const float* lnw  = (const float*)d_in[1];
    const float* lnb  = (const float*)d_in[2];
    const float* bw1  = (const float*)d_in[3];
    const float* sw1  = (const float*)d_in[4];
    const float* ss1  = (const float*)d_in[5];
    const float* bw2  = (const float*)d_in[6];
    const float* sw2  = (const float*)d_in[7];
    const float* ss2  = (const float*)d_in[8];

    char* ws = (char*)d_ws;
    uint16_t* w1L = (uint16_t*)ws;                          // 36,864 B
    uint16_t* w2p = (uint16_t*)(ws + 65536);                // 2,359,296 B
    uint16_t* a2  = (uint16_t*)(ws + 65536 + 2359296);      // 75,497,472 B
    float* out = (float*)d_out;

    pack_w1<<<dim3(72), dim3(256), 0, stream>>>(bw1, sw1, ss1, w1L);
    pack_w2<<<dim3((NOUT * K2 + 255) / 256), dim3(256), 0, stream>>>(bw2, sw2, ss2, w2p);
    featurize<<<dim3(BATCH / FBR), dim3(256), 0, stream>>>(x, lnw, lnb, w1L, a2);
    gemm2_kernel<<<dim3((BATCH / BM) * (NOUT / BN)), dim3(512), 0, stream>>>(a2, w2p, out);
}